// Round 19
// baseline (101.556 us; speedup 1.0000x reference)
//
#include <hip/hip_runtime.h>

typedef __bf16 bf16;
typedef __attribute__((ext_vector_type(4))) bf16 bf16x4;
typedef __attribute__((ext_vector_type(8))) bf16 bf16x8;
typedef __attribute__((ext_vector_type(4))) float f32x4;

#define MFMA16(a, b, c) __builtin_amdgcn_mfma_f32_16x16x32_bf16(a, b, c, 0, 0, 0)
#define EXP2F(x) __builtin_amdgcn_exp2f(x)

constexpr int Bb = 4, Ss = 4096, Ee = 1024, Hh = 128;
constexpr int Mrows = Bb * Ss;  // 16384
constexpr int QB = 256;         // attn q-block (8 waves x 32 rows)
constexpr int NQB = Ss / QB;    // 16

// ---------------------------------------------------------------------------
// Kernel 0: build fragment-major Wfrag DIRECTLY from W.
// grid (24, 4): S x k-quarter (256 k each). block 256.
// ---------------------------------------------------------------------------
__global__ __launch_bounds__(256) void wfrag_kernel(
    const float* __restrict__ Wq, const float* __restrict__ Wk,
    const float* __restrict__ Wv, bf16* __restrict__ Wfrag)
{
    __shared__ bf16 Sb[256][18];    // [k][col], padded row = 36B
    const int S = blockIdx.x, kq = blockIdx.y, t = threadIdx.x;
    const float* W = ((S >> 3) == 0) ? Wq : ((S >> 3) == 1) ? Wk : Wv;
    const int c0 = (S & 7) * 16, k0 = kq * 256;
    {
        const float4* src = (const float4*)(W + (size_t)(k0 + t) * Hh + c0);
        #pragma unroll
        for (int q = 0; q < 4; ++q) {
            float4 v = src[q];
            bf16x4 o; o[0] = (bf16)v.x; o[1] = (bf16)v.y; o[2] = (bf16)v.z; o[3] = (bf16)v.w;
            *(bf16x4*)&Sb[t][q * 4] = o;
        }
    }
    __syncthreads();
    const int lane = t & 63;
    #pragma unroll
    for (int r = 0; r < 2; ++r) {
        int ksl = (t >> 6) + 4 * r;
        int kb = ksl * 32 + (lane >> 4) * 8;
        bf16x8 o;
        #pragma unroll
        for (int j = 0; j < 8; ++j) o[j] = Sb[kb + j][lane & 15];
        *(bf16x8*)&Wfrag[(((size_t)S * 32 + kq * 8 + ksl) * 64 + lane) * 8] = o;
    }
}

// ---------------------------------------------------------------------------
// Kernel 1: fused QKV projection — 64-row A panel, HALF-PIPELINED staging.
// grid (Mrows/64) = 256 (1 block/CU), block 512 (8 waves).
// Stage k[0,512) -> LDS, barrier; ISSUE k[512,1024) into 16 float4 regs;
// compute ks 0..15 on half 0 (HBM latency of half 1 hides under MFMA);
// at ks==16 convert+write half 1, barrier; compute ks 16..31.
// k-loop: 4 ds_read_b128 A-frags + 3 coalesced 1KB B loads (depth-2 reg
// prefetch) + 12 MFMA per step. Wave wv owns col-frags F = 3wv..3wv+2.
// V written transposed: Vtg[b][h][s]. Q pre-scaled by log2(e)/sqrt(H).
// ---------------------------------------------------------------------------
__global__ __launch_bounds__(512) void proj_kernel(
    const float* __restrict__ embds, const bf16* __restrict__ Wfrag,
    const float* __restrict__ bq, const float* __restrict__ bk,
    const float* __restrict__ bv,
    bf16* __restrict__ Qb, bf16* __restrict__ Kb, bf16* __restrict__ Vtg)
{
    __shared__ bf16 As[2][64][512];   // 2 x 64 KB; chunk c at c^(row&15)

    const int t = threadIdx.x;
    const int wv = t >> 6, lane = t & 63, lo = lane & 15, hi = lane >> 4;
    const int m0 = blockIdx.x * 64;

    const int arow = t >> 3;
    const float4* asrc = (const float4*)(embds + (size_t)(m0 + arow) * Ee) + (t & 7) * 16;
    float4 v[16];

    // ---- half 0: load + convert + write ----
    #pragma unroll
    for (int j = 0; j < 16; ++j) v[j] = asrc[j];
    #pragma unroll
    for (int jj = 0; jj < 8; ++jj) {
        bf16x8 o;
        o[0] = (bf16)v[2*jj].x; o[1] = (bf16)v[2*jj].y;
        o[2] = (bf16)v[2*jj].z; o[3] = (bf16)v[2*jj].w;
        o[4] = (bf16)v[2*jj+1].x; o[5] = (bf16)v[2*jj+1].y;
        o[6] = (bf16)v[2*jj+1].z; o[7] = (bf16)v[2*jj+1].w;
        *(bf16x8*)&As[0][arow][(((t & 7) * 8 + jj) ^ (arow & 15)) * 8] = o;
    }
    __syncthreads();
    // ---- issue half-1 loads (consumed at ks==16) ----
    #pragma unroll
    for (int j = 0; j < 16; ++j) v[j] = asrc[128 + j];

    f32x4 acc[4][3];
    #pragma unroll
    for (int rg = 0; rg < 4; ++rg)
        #pragma unroll
        for (int f = 0; f < 3; ++f) acc[rg][f] = f32x4{0.f, 0.f, 0.f, 0.f};

    const bf16* bp0 = Wfrag + ((size_t)(wv * 3 + 0) * 32) * 512 + lane * 8;
    const bf16* bp1 = Wfrag + ((size_t)(wv * 3 + 1) * 32) * 512 + lane * 8;
    const bf16* bp2 = Wfrag + ((size_t)(wv * 3 + 2) * 32) * 512 + lane * 8;

    bf16x8 c0 = *(const bf16x8*)(bp0);
    bf16x8 c1 = *(const bf16x8*)(bp1);
    bf16x8 c2 = *(const bf16x8*)(bp2);
    bf16x8 n0 = *(const bf16x8*)(bp0 + 512);
    bf16x8 n1 = *(const bf16x8*)(bp1 + 512);
    bf16x8 n2 = *(const bf16x8*)(bp2 + 512);

    #pragma unroll
    for (int ks = 0; ks < 32; ++ks) {
        if (ks == 16) {   // write half 1 (loads issued before the loop)
            #pragma unroll
            for (int jj = 0; jj < 8; ++jj) {
                bf16x8 o;
                o[0] = (bf16)v[2*jj].x; o[1] = (bf16)v[2*jj].y;
                o[2] = (bf16)v[2*jj].z; o[3] = (bf16)v[2*jj].w;
                o[4] = (bf16)v[2*jj+1].x; o[5] = (bf16)v[2*jj+1].y;
                o[6] = (bf16)v[2*jj+1].z; o[7] = (bf16)v[2*jj+1].w;
                *(bf16x8*)&As[1][arow][(((t & 7) * 8 + jj) ^ (arow & 15)) * 8] = o;
            }
            __syncthreads();
        }
        const int h = ks >> 4, ksl = ks & 15;
        const int pos = ((ksl * 4 + hi) ^ lo) * 8;
        bf16x8 a0 = *(const bf16x8*)&As[h][lo][pos];
        bf16x8 a1 = *(const bf16x8*)&As[h][16 + lo][pos];
        bf16x8 a2 = *(const bf16x8*)&As[h][32 + lo][pos];
        bf16x8 a3 = *(const bf16x8*)&As[h][48 + lo][pos];
        __builtin_amdgcn_s_setprio(1);
        acc[0][0] = MFMA16(a0, c0, acc[0][0]);
        acc[1][0] = MFMA16(a1, c0, acc[1][0]);
        acc[2][0] = MFMA16(a2, c0, acc[2][0]);
        acc[3][0] = MFMA16(a3, c0, acc[3][0]);
        acc[0][1] = MFMA16(a0, c1, acc[0][1]);
        acc[1][1] = MFMA16(a1, c1, acc[1][1]);
        acc[2][1] = MFMA16(a2, c1, acc[2][1]);
        acc[3][1] = MFMA16(a3, c1, acc[3][1]);
        acc[0][2] = MFMA16(a0, c2, acc[0][2]);
        acc[1][2] = MFMA16(a1, c2, acc[1][2]);
        acc[2][2] = MFMA16(a2, c2, acc[2][2]);
        acc[3][2] = MFMA16(a3, c2, acc[3][2]);
        __builtin_amdgcn_s_setprio(0);
        c0 = n0; c1 = n1; c2 = n2;
        if (ks + 2 < 32) {
            n0 = *(const bf16x8*)(bp0 + (ks + 2) * 512);
            n1 = *(const bf16x8*)(bp1 + (ks + 2) * 512);
            n2 = *(const bf16x8*)(bp2 + (ks + 2) * 512);
        }
    }

    #pragma unroll
    for (int f = 0; f < 3; ++f) {
        const int F = wv * 3 + f;
        const int p = F >> 3;
        const int col = (F & 7) * 16 + lo;
        const float* bias = (p == 0) ? bq : (p == 1) ? bk : bv;
        float bvv = bias[col];
        if (p == 2) {
            const int mb = m0 >> 12, s0l = m0 & 4095;
            #pragma unroll
            for (int rg = 0; rg < 4; ++rg)
                #pragma unroll
                for (int i = 0; i < 4; ++i) {
                    int s = s0l + rg * 16 + hi * 4 + i;
                    Vtg[((size_t)mb * Hh + col) * Ss + s] = (bf16)(acc[rg][f][i] + bvv);
                }
        } else {
            bf16* dst = (p == 0) ? Qb : Kb;
            // Q scale = log2(e)/sqrt(128): softmax runs in exp2 domain
            const float scale = (p == 0) ? 0.1275174407017663f : 1.0f;
            #pragma unroll
            for (int rg = 0; rg < 4; ++rg)
                #pragma unroll
                for (int i = 0; i < 4; ++i) {
                    int row = m0 + rg * 16 + hi * 4 + i;
                    dst[(size_t)row * Hh + col] = (bf16)((acc[rg][f][i] + bvv) * scale);
                }
        }
    }
}

// ---------------------------------------------------------------------------
// Kernel 2: split-KV causal flash attention, swapped QK^T, QBLK=256,
// KVBLK=64 (r17 config: 2 blocks/CU). exp2 softmax + defer-max + packed P +
// bf16 partials. grid (CH, B); nchunks(qb) = ceil((4qb+4)/DIV).
// ---------------------------------------------------------------------------
__global__ __launch_bounds__(512, 2) void attn_kernel(
    const bf16* __restrict__ Qb, const bf16* __restrict__ Kb,
    const bf16* __restrict__ Vtg,
    bf16* __restrict__ Opart, float* __restrict__ Mpart, float* __restrict__ Lpart,
    int DIV, int CH)
{
    __shared__ bf16 Ks[64][136];   // K tile, stride 272B
    __shared__ bf16 Vt[128][64];   // V^T tile, (h&7)-XOR swizzled 16B chunks
    __shared__ bf16 Ps[8][32][72]; // wave-private P[q][kv]

    const int t = threadIdx.x;
    const int wv = t >> 6, lane = t & 63, lo = lane & 15, hi = lane >> 4;
    const int slot = blockIdx.x, b = blockIdx.y;

    int u = slot, qb = 0, nch = 1;
    for (qb = 0; qb < NQB; ++qb) {
        nch = (4 * qb + 4 + DIV - 1) / DIV;
        if (u < nch) break;
        u -= nch;
    }
    const int ntiles = 4 * qb + 4;
    const int t0 = (u * ntiles) / nch;
    const int t1 = ((u + 1) * ntiles) / nch;

    const int q0 = qb * QB;
    const size_t base = (size_t)b * Ss * Hh;
    const size_t vbase = (size_t)b * Hh * Ss;

    const bf16* kg = Kb + base + (size_t)(t >> 4) * Hh + (t & 15) * 8;
    const bf16* vg = Vtg + vbase + (size_t)(t >> 3) * Ss + (t & 7) * 8;
    bf16* ksl = &Ks[t >> 4][(t & 15) * 8];
    bf16* vsl = &Vt[t >> 3][((t & 7) * 8) ^ (((t >> 3) & 7) << 3)];

    bf16x8 qf[2][4];
    #pragma unroll
    for (int g = 0; g < 2; ++g)
        #pragma unroll
        for (int kk = 0; kk < 4; ++kk)
            qf[g][kk] = *(const bf16x8*)(
                Qb + base + (size_t)(q0 + wv * 32 + g * 16 + lo) * Hh + kk * 32 + hi * 8);

    f32x4 acc[2][8];
    #pragma unroll
    for (int g = 0; g < 2; ++g)
        #pragma unroll
        for (int f = 0; f < 8; ++f) acc[g][f] = f32x4{0.f, 0.f, 0.f, 0.f};
    float M_[2] = {-1e30f, -1e30f};
    float L_[2] = {0.f, 0.f};

    uint4 kr0, kr1, vr0, vr1;
#define ISSUE(T) do {                                            \
        const bf16* kp_ = kg + (size_t)(T) * (64 * Hh);          \
        kr0 = *(const uint4*)(kp_);                              \
        kr1 = *(const uint4*)(kp_ + 32 * Hh);                    \
        const bf16* vp_ = vg + (T) * 64;                         \
        vr0 = *(const uint4*)(vp_);                              \
        vr1 = *(const uint4*)(vp_ + 64 * Ss);                    \
    } while (0)

    ISSUE(t0);
    for (int tile = t0; tile < t1; ++tile) {
        __syncthreads();
        *(uint4*)(ksl) = kr0;
        *(uint4*)(ksl + 32 * 136) = kr1;
        *(uint4*)(vsl) = vr0;
        *(uint4*)(vsl + 64 * 64) = vr1;
        if (tile + 1 < t1) ISSUE(tile + 1);
        __syncthreads();
        const int kv0 = tile * 64;

        f32x4 sv[2][4];
        #pragma unroll
        for (int g = 0; g < 2; ++g)
            #pragma unroll
            for (int f = 0; f < 4; ++f) sv[g][f] = f32x4{0.f, 0.f, 0.f, 0.f};
        __builtin_amdgcn_s_setprio(1);
        #pragma unroll
        for (int kk = 0; kk < 4; ++kk) {
            #pragma unroll
            for (int f = 0; f < 4; ++f) {
                bf16x8 kf = *(const bf16x8*)&Ks[f * 16 + lo][kk * 32 + hi * 8];
                sv[0][f] = MFMA16(kf, qf[0][kk], sv[0][f]);
                sv[1][f] = MFMA16(kf, qf[1][kk], sv[1][f]);
            }
        }
        __builtin_amdgcn_s_setprio(0);

        #pragma unroll
        for (int g = 0; g < 2; ++g) {
            const int qg0 = q0 + wv * 32 + g * 16;
            if (kv0 + 63 > qg0) {
                int qg = qg0 + lo;
                #pragma unroll
                for (int f = 0; f < 4; ++f)
                    #pragma unroll
                    for (int i = 0; i < 4; ++i)
                        if (kv0 + f * 16 + hi * 4 + i > qg) sv[g][f][i] = -INFINITY;
            }
            float pm = -INFINITY;
            #pragma unroll
            for (int f = 0; f < 4; ++f)
                pm = fmaxf(pm, fmaxf(fmaxf(sv[g][f][0], sv[g][f][1]),
                                     fmaxf(sv[g][f][2], sv[g][f][3])));
            pm = fmaxf(pm, __shfl_xor(pm, 16));
            pm = fmaxf(pm, __shfl_xor(pm, 32));
            if (!__all(pm - M_[g] <= 8.f)) {
                float nM = fmaxf(M_[g], pm);
                float scn = EXP2F(M_[g] - nM);
                L_[g] *= scn;
                #pragma unroll
                for (int i = 0; i < 4; ++i) {
                    float si = __shfl(scn, (lane & 48) + hi * 4 + i);
                    #pragma unroll
                    for (int f = 0; f < 8; ++f) acc[g][f][i] *= si;
                }
                M_[g] = nM;
            }
            float rs = 0.f;
            #pragma unroll
            for (int f = 0; f < 4; ++f) {
                bf16x4 p;
                #pragma unroll
                for (int i = 0; i < 4; ++i) {
                    float e = EXP2F(sv[g][f][i] - M_[g]);
                    p[i] = (bf16)e;
                    rs += e;
                }
                *(bf16x4*)&Ps[wv][g * 16 + lo][f * 16 + hi * 4] = p;
            }
            rs += __shfl_xor(rs, 16);
            rs += __shfl_xor(rs, 32);
            L_[g] += rs;
        }
        __builtin_amdgcn_s_setprio(1);
        #pragma unroll
        for (int kk = 0; kk < 2; ++kk) {
            bf16x8 pa0 = *(const bf16x8*)&Ps[wv][lo][kk * 32 + hi * 8];
            bf16x8 pa1 = *(const bf16x8*)&Ps[wv][16 + lo][kk * 32 + hi * 8];
            #pragma unroll
            for (int f = 0; f < 8; ++f) {
                int row = f * 16 + lo;
                bf16x8 vf = *(const bf16x8*)&Vt[row][(kk * 32 + hi * 8) ^ ((row & 7) << 3)];
                acc[0][f] = MFMA16(pa0, vf, acc[0][f]);
                acc[1][f] = MFMA16(pa1, vf, acc[1][f]);
            }
        }
        __builtin_amdgcn_s_setprio(0);
    }
#undef ISSUE
    const size_t pb = ((size_t)b * CH + slot) * QB;
    #pragma unroll
    for (int g = 0; g < 2; ++g)
        #pragma unroll
        for (int f = 0; f < 8; ++f)
            #pragma unroll
            for (int i = 0; i < 4; ++i) {
                int row = wv * 32 + g * 16 + hi * 4 + i;
                Opart[(pb + row) * 128 + f * 16 + lo] = (bf16)acc[g][f][i];
            }
    if (hi == 0) {
        #pragma unroll
        for (int g = 0; g < 2; ++g) {
            Mpart[pb + wv * 32 + g * 16 + lo] = M_[g];
            Lpart[pb + wv * 32 + g * 16 + lo] = L_[g];
        }
    }
}

// ---------------------------------------------------------------------------
// Kernel 3: combine chunk partials (exp2 domain, bf16 partials).
// grid (NQB*2, B), block 256; each block handles a 128-row half of a q-block.
// ---------------------------------------------------------------------------
__global__ __launch_bounds__(256) void reduce_kernel(
    const bf16* __restrict__ Opart, const float* __restrict__ Mpart,
    const float* __restrict__ Lpart, float* __restrict__ out, int DIV, int CH)
{
    __shared__ float wexp[7][128];
    __shared__ float invL[128];
    const int qb = blockIdx.x >> 1, half = blockIdx.x & 1;
    const int b = blockIdx.y, t = threadIdx.x;
    const int r0 = half * 128;
    int pbase = 0, nact = 1;
    for (int j = 0; j <= qb; ++j) {
        int n = (4 * j + 4 + DIV - 1) / DIV;
        if (j == qb) { nact = n; break; }
        pbase += n;
    }
    const size_t pb = ((size_t)b * CH + pbase) * QB;
    if (t < 128) {
        float Mstar = -INFINITY;
        for (int c = 0; c < nact; ++c)
            Mstar = fmaxf(Mstar, Mpart[pb + c * QB + r0 + t]);
        float Ls = 0.f;
        for (int c = 0; c < nact; ++c) {
            float wc = __builtin_amdgcn_exp2f(Mpart[pb + c * QB + r0 + t] - Mstar);
            wexp[c][t] = wc;
            Ls += wc * Lpart[pb + c * QB + r0 + t];
        }
        invL[t] = 1.f / Ls;
    }
    __syncthreads();
    #pragma unroll
    for (int rep = 0; rep < 16; ++rep) {
        int idx = rep * 256 + t;
        int row = idx >> 5, c4 = (idx & 31) * 4;
        float ox = 0.f, oy = 0.f, oz = 0.f, ow = 0.f;
        for (int c = 0; c < nact; ++c) {
            float wc = wexp[c][row];
            bf16x4 v = *(const bf16x4*)(Opart + (pb + (size_t)c * QB + r0 + row) * 128 + c4);
            ox += wc * (float)v[0]; oy += wc * (float)v[1];
            oz += wc * (float)v[2]; ow += wc * (float)v[3];
        }
        float il = invL[row];
        float4 o = make_float4(ox * il, oy * il, oz * il, ow * il);
        *(float4*)(out + ((size_t)b * Ss + qb * QB + r0 + row) * 128 + c4) = o;
    }
}

extern "C" void kernel_launch(void* const* d_in, const int* in_sizes, int n_in,
                              void* d_out, int out_size, void* d_ws, size_t ws_size,
                              hipStream_t stream) {
    (void)in_sizes; (void)n_in; (void)out_size;
    const float* embds = (const float*)d_in[0];
    const float* Wq = (const float*)d_in[1];
    const float* bq = (const float*)d_in[2];
    const float* Wk = (const float*)d_in[3];
    const float* bk = (const float*)d_in[4];
    const float* Wv = (const float*)d_in[5];
    const float* bv = (const float*)d_in[6];

    char* ws = (char*)d_ws;
    size_t off = 0;
    bf16* Qb    = (bf16*)(ws + off); off += (size_t)Mrows * Hh * 2;
    bf16* Kb    = (bf16*)(ws + off); off += (size_t)Mrows * Hh * 2;
    bf16* Vtg   = (bf16*)(ws + off); off += (size_t)Mrows * Hh * 2;
    bf16* Wfrag = (bf16*)(ws + off); off += (size_t)3 * Hh * Ee * 2;

    auto chunks_for = [](int div) {
        int s = 0;
        for (int qb = 0; qb < NQB; ++qb) s += (4 * qb + 4 + div - 1) / div;
        return s;
    };
    auto need = [&](int ch) {
        return off + (size_t)Bb * ch * QB * 128 * 2 + (size_t)Bb * ch * QB * 8;
    };
    int DIV = 10;
    int CH = chunks_for(DIV);                     // 61
    if (need(CH) > ws_size) { DIV = 20; CH = chunks_for(DIV); }
    bf16* Opart = (bf16*)(ws + off);
    size_t osz = (size_t)Bb * CH * QB * 128 * 2;
    float* Mp = (float*)(ws + off + osz);
    float* Lp = Mp + (size_t)Bb * CH * QB;

    wfrag_kernel<<<dim3(24, 4), 256, 0, stream>>>(Wq, Wk, Wv, Wfrag);
    proj_kernel<<<dim3(Mrows / 64), 512, 0, stream>>>(embds, Wfrag, bq, bk, bv, Qb, Kb, Vtg);
    attn_kernel<<<dim3(CH, Bb), 512, 0, stream>>>(Qb, Kb, Vtg, Opart, Mp, Lp, DIV, CH);
    reduce_kernel<<<dim3(NQB * 2, Bb), 256, 0, stream>>>(Opart, Mp, Lp, (float*)d_out, DIV, CH);
}

// Round 20
// 99.156 us; speedup vs baseline: 1.0242x; 1.0242x over previous
//
#include <hip/hip_runtime.h>

typedef __bf16 bf16;
typedef __attribute__((ext_vector_type(4))) bf16 bf16x4;
typedef __attribute__((ext_vector_type(8))) bf16 bf16x8;
typedef __attribute__((ext_vector_type(4))) float f32x4;

#define MFMA16(a, b, c) __builtin_amdgcn_mfma_f32_16x16x32_bf16(a, b, c, 0, 0, 0)
#define EXP2F(x) __builtin_amdgcn_exp2f(x)

constexpr int Bb = 4, Ss = 4096, Ee = 1024, Hh = 128;
constexpr int Mrows = Bb * Ss;  // 16384
constexpr int QB = 256;         // attn q-block (8 waves x 32 rows)
constexpr int NQB = Ss / QB;    // 16

// ---------------------------------------------------------------------------
// Kernel 0: build fragment-major Wfrag DIRECTLY from W.
// grid (24, 4): S x k-quarter (256 k each). block 256.
// ---------------------------------------------------------------------------
__global__ __launch_bounds__(256) void wfrag_kernel(
    const float* __restrict__ Wq, const float* __restrict__ Wk,
    const float* __restrict__ Wv, bf16* __restrict__ Wfrag)
{
    __shared__ bf16 Sb[256][18];    // [k][col], padded row = 36B
    const int S = blockIdx.x, kq = blockIdx.y, t = threadIdx.x;
    const float* W = ((S >> 3) == 0) ? Wq : ((S >> 3) == 1) ? Wk : Wv;
    const int c0 = (S & 7) * 16, k0 = kq * 256;
    {
        const float4* src = (const float4*)(W + (size_t)(k0 + t) * Hh + c0);
        #pragma unroll
        for (int q = 0; q < 4; ++q) {
            float4 v = src[q];
            bf16x4 o; o[0] = (bf16)v.x; o[1] = (bf16)v.y; o[2] = (bf16)v.z; o[3] = (bf16)v.w;
            *(bf16x4*)&Sb[t][q * 4] = o;
        }
    }
    __syncthreads();
    const int lane = t & 63;
    #pragma unroll
    for (int r = 0; r < 2; ++r) {
        int ksl = (t >> 6) + 4 * r;
        int kb = ksl * 32 + (lane >> 4) * 8;
        bf16x8 o;
        #pragma unroll
        for (int j = 0; j < 8; ++j) o[j] = Sb[kb + j][lane & 15];
        *(bf16x8*)&Wfrag[(((size_t)S * 32 + kq * 8 + ksl) * 64 + lane) * 8] = o;
    }
}

// ---------------------------------------------------------------------------
// Kernel 1: fused QKV projection — 64-row A-resident panel (128 KB LDS) +
// fragment-major B (r17-best config). grid (Mrows/64) = 256, block 512.
// ---------------------------------------------------------------------------
__global__ __launch_bounds__(512) void proj_kernel(
    const float* __restrict__ embds, const bf16* __restrict__ Wfrag,
    const float* __restrict__ bq, const float* __restrict__ bk,
    const float* __restrict__ bv,
    bf16* __restrict__ Qb, bf16* __restrict__ Kb, bf16* __restrict__ Vtg)
{
    __shared__ bf16 As[64][1024];   // 128 KB; 16B chunk c stored at c^(row&15)

    const int t = threadIdx.x;
    const int wv = t >> 6, lane = t & 63, lo = lane & 15, hi = lane >> 4;
    const int m0 = blockIdx.x * 64;

    {
        const int row = t >> 3, cb = (t & 7) * 16;
        const float4* src = (const float4*)(embds + (size_t)(m0 + row) * Ee + (t & 7) * 128);
        #pragma unroll
        for (int half = 0; half < 2; ++half) {
            float4 v[16];
            #pragma unroll
            for (int jj = 0; jj < 16; ++jj) v[jj] = src[half * 16 + jj];
            #pragma unroll
            for (int jj = 0; jj < 8; ++jj) {
                bf16x8 o;
                o[0] = (bf16)v[2*jj].x; o[1] = (bf16)v[2*jj].y;
                o[2] = (bf16)v[2*jj].z; o[3] = (bf16)v[2*jj].w;
                o[4] = (bf16)v[2*jj+1].x; o[5] = (bf16)v[2*jj+1].y;
                o[6] = (bf16)v[2*jj+1].z; o[7] = (bf16)v[2*jj+1].w;
                *(bf16x8*)&As[row][((cb + half * 8 + jj) ^ (row & 15)) * 8] = o;
            }
        }
    }
    __syncthreads();

    f32x4 acc[4][3];
    #pragma unroll
    for (int rg = 0; rg < 4; ++rg)
        #pragma unroll
        for (int f = 0; f < 3; ++f) acc[rg][f] = f32x4{0.f, 0.f, 0.f, 0.f};

    const bf16* bp0 = Wfrag + ((size_t)(wv * 3 + 0) * 32) * 512 + lane * 8;
    const bf16* bp1 = Wfrag + ((size_t)(wv * 3 + 1) * 32) * 512 + lane * 8;
    const bf16* bp2 = Wfrag + ((size_t)(wv * 3 + 2) * 32) * 512 + lane * 8;

    bf16x8 c0 = *(const bf16x8*)(bp0);
    bf16x8 c1 = *(const bf16x8*)(bp1);
    bf16x8 c2 = *(const bf16x8*)(bp2);
    bf16x8 n0 = *(const bf16x8*)(bp0 + 512);
    bf16x8 n1 = *(const bf16x8*)(bp1 + 512);
    bf16x8 n2 = *(const bf16x8*)(bp2 + 512);

    #pragma unroll
    for (int ks = 0; ks < 32; ++ks) {
        const int pos = ((ks * 4 + hi) ^ lo) * 8;
        bf16x8 a0 = *(const bf16x8*)&As[lo][pos];
        bf16x8 a1 = *(const bf16x8*)&As[16 + lo][pos];
        bf16x8 a2 = *(const bf16x8*)&As[32 + lo][pos];
        bf16x8 a3 = *(const bf16x8*)&As[48 + lo][pos];
        __builtin_amdgcn_s_setprio(1);
        acc[0][0] = MFMA16(a0, c0, acc[0][0]);
        acc[1][0] = MFMA16(a1, c0, acc[1][0]);
        acc[2][0] = MFMA16(a2, c0, acc[2][0]);
        acc[3][0] = MFMA16(a3, c0, acc[3][0]);
        acc[0][1] = MFMA16(a0, c1, acc[0][1]);
        acc[1][1] = MFMA16(a1, c1, acc[1][1]);
        acc[2][1] = MFMA16(a2, c1, acc[2][1]);
        acc[3][1] = MFMA16(a3, c1, acc[3][1]);
        acc[0][2] = MFMA16(a0, c2, acc[0][2]);
        acc[1][2] = MFMA16(a1, c2, acc[1][2]);
        acc[2][2] = MFMA16(a2, c2, acc[2][2]);
        acc[3][2] = MFMA16(a3, c2, acc[3][2]);
        __builtin_amdgcn_s_setprio(0);
        c0 = n0; c1 = n1; c2 = n2;
        if (ks + 2 < 32) {
            n0 = *(const bf16x8*)(bp0 + (ks + 2) * 512);
            n1 = *(const bf16x8*)(bp1 + (ks + 2) * 512);
            n2 = *(const bf16x8*)(bp2 + (ks + 2) * 512);
        }
    }

    #pragma unroll
    for (int f = 0; f < 3; ++f) {
        const int F = wv * 3 + f;
        const int p = F >> 3;
        const int col = (F & 7) * 16 + lo;
        const float* bias = (p == 0) ? bq : (p == 1) ? bk : bv;
        float bvv = bias[col];
        if (p == 2) {
            const int mb = m0 >> 12, s0l = m0 & 4095;
            #pragma unroll
            for (int rg = 0; rg < 4; ++rg)
                #pragma unroll
                for (int i = 0; i < 4; ++i) {
                    int s = s0l + rg * 16 + hi * 4 + i;
                    Vtg[((size_t)mb * Hh + col) * Ss + s] = (bf16)(acc[rg][f][i] + bvv);
                }
        } else {
            bf16* dst = (p == 0) ? Qb : Kb;
            // Q scale = log2(e)/sqrt(128): softmax runs in exp2 domain
            const float scale = (p == 0) ? 0.1275174407017663f : 1.0f;
            #pragma unroll
            for (int rg = 0; rg < 4; ++rg)
                #pragma unroll
                for (int i = 0; i < 4; ++i) {
                    int row = m0 + rg * 16 + hi * 4 + i;
                    dst[(size_t)row * Hh + col] = (bf16)((acc[rg][f][i] + bvv) * scale);
                }
        }
    }
}

// ---------------------------------------------------------------------------
// Kernel 2: split-KV causal flash attention (r17-best config: QBLK=256,
// KVBLK=64, 2 blocks/CU) + T1 bijective XCD slot swizzle. exp2 softmax +
// defer-max + packed P + bf16 partials. grid (CH, B).
// ---------------------------------------------------------------------------
__global__ __launch_bounds__(512, 2) void attn_kernel(
    const bf16* __restrict__ Qb, const bf16* __restrict__ Kb,
    const bf16* __restrict__ Vtg,
    bf16* __restrict__ Opart, float* __restrict__ Mpart, float* __restrict__ Lpart,
    int DIV, int CH)
{
    __shared__ bf16 Ks[64][136];   // K tile, stride 272B
    __shared__ bf16 Vt[128][64];   // V^T tile, (h&7)-XOR swizzled 16B chunks
    __shared__ bf16 Ps[8][32][72]; // wave-private P[q][kv]

    const int t = threadIdx.x;
    const int wv = t >> 6, lane = t & 63, lo = lane & 15, hi = lane >> 4;
    // T1: bijective XCD swizzle (m204): consecutive slots -> same XCD
    int slot;
    {
        const int o = blockIdx.x, q = CH >> 3, r = CH & 7;
        const int xcd = o & 7, idx = o >> 3;
        slot = (xcd < r ? xcd * (q + 1) : r * (q + 1) + (xcd - r) * q) + idx;
        if (slot >= CH) slot = o;   // safety (unreachable for valid o)
    }
    const int b = blockIdx.y;

    int u = slot, qb = 0, nch = 1;
    for (qb = 0; qb < NQB; ++qb) {
        nch = (4 * qb + 4 + DIV - 1) / DIV;
        if (u < nch) break;
        u -= nch;
    }
    const int ntiles = 4 * qb + 4;
    const int t0 = (u * ntiles) / nch;
    const int t1 = ((u + 1) * ntiles) / nch;

    const int q0 = qb * QB;
    const size_t base = (size_t)b * Ss * Hh;
    const size_t vbase = (size_t)b * Hh * Ss;

    const bf16* kg = Kb + base + (size_t)(t >> 4) * Hh + (t & 15) * 8;
    const bf16* vg = Vtg + vbase + (size_t)(t >> 3) * Ss + (t & 7) * 8;
    bf16* ksl = &Ks[t >> 4][(t & 15) * 8];
    bf16* vsl = &Vt[t >> 3][((t & 7) * 8) ^ (((t >> 3) & 7) << 3)];

    bf16x8 qf[2][4];
    #pragma unroll
    for (int g = 0; g < 2; ++g)
        #pragma unroll
        for (int kk = 0; kk < 4; ++kk)
            qf[g][kk] = *(const bf16x8*)(
                Qb + base + (size_t)(q0 + wv * 32 + g * 16 + lo) * Hh + kk * 32 + hi * 8);

    f32x4 acc[2][8];
    #pragma unroll
    for (int g = 0; g < 2; ++g)
        #pragma unroll
        for (int f = 0; f < 8; ++f) acc[g][f] = f32x4{0.f, 0.f, 0.f, 0.f};
    float M_[2] = {-1e30f, -1e30f};
    float L_[2] = {0.f, 0.f};

    uint4 kr0, kr1, vr0, vr1;
#define ISSUE(T) do {                                            \
        const bf16* kp_ = kg + (size_t)(T) * (64 * Hh);          \
        kr0 = *(const uint4*)(kp_);                              \
        kr1 = *(const uint4*)(kp_ + 32 * Hh);                    \
        const bf16* vp_ = vg + (T) * 64;                         \
        vr0 = *(const uint4*)(vp_);                              \
        vr1 = *(const uint4*)(vp_ + 64 * Ss);                    \
    } while (0)

    ISSUE(t0);
    for (int tile = t0; tile < t1; ++tile) {
        __syncthreads();
        *(uint4*)(ksl) = kr0;
        *(uint4*)(ksl + 32 * 136) = kr1;
        *(uint4*)(vsl) = vr0;
        *(uint4*)(vsl + 64 * 64) = vr1;
        if (tile + 1 < t1) ISSUE(tile + 1);
        __syncthreads();
        const int kv0 = tile * 64;

        f32x4 sv[2][4];
        #pragma unroll
        for (int g = 0; g < 2; ++g)
            #pragma unroll
            for (int f = 0; f < 4; ++f) sv[g][f] = f32x4{0.f, 0.f, 0.f, 0.f};
        __builtin_amdgcn_s_setprio(1);
        #pragma unroll
        for (int kk = 0; kk < 4; ++kk) {
            #pragma unroll
            for (int f = 0; f < 4; ++f) {
                bf16x8 kf = *(const bf16x8*)&Ks[f * 16 + lo][kk * 32 + hi * 8];
                sv[0][f] = MFMA16(kf, qf[0][kk], sv[0][f]);
                sv[1][f] = MFMA16(kf, qf[1][kk], sv[1][f]);
            }
        }
        __builtin_amdgcn_s_setprio(0);

        #pragma unroll
        for (int g = 0; g < 2; ++g) {
            const int qg0 = q0 + wv * 32 + g * 16;
            if (kv0 + 63 > qg0) {
                int qg = qg0 + lo;
                #pragma unroll
                for (int f = 0; f < 4; ++f)
                    #pragma unroll
                    for (int i = 0; i < 4; ++i)
                        if (kv0 + f * 16 + hi * 4 + i > qg) sv[g][f][i] = -INFINITY;
            }
            float pm = -INFINITY;
            #pragma unroll
            for (int f = 0; f < 4; ++f)
                pm = fmaxf(pm, fmaxf(fmaxf(sv[g][f][0], sv[g][f][1]),
                                     fmaxf(sv[g][f][2], sv[g][f][3])));
            pm = fmaxf(pm, __shfl_xor(pm, 16));
            pm = fmaxf(pm, __shfl_xor(pm, 32));
            if (!__all(pm - M_[g] <= 8.f)) {
                float nM = fmaxf(M_[g], pm);
                float scn = EXP2F(M_[g] - nM);
                L_[g] *= scn;
                #pragma unroll
                for (int i = 0; i < 4; ++i) {
                    float si = __shfl(scn, (lane & 48) + hi * 4 + i);
                    #pragma unroll
                    for (int f = 0; f < 8; ++f) acc[g][f][i] *= si;
                }
                M_[g] = nM;
            }
            float rs = 0.f;
            #pragma unroll
            for (int f = 0; f < 4; ++f) {
                bf16x4 p;
                #pragma unroll
                for (int i = 0; i < 4; ++i) {
                    float e = EXP2F(sv[g][f][i] - M_[g]);
                    p[i] = (bf16)e;
                    rs += e;
                }
                *(bf16x4*)&Ps[wv][g * 16 + lo][f * 16 + hi * 4] = p;
            }
            rs += __shfl_xor(rs, 16);
            rs += __shfl_xor(rs, 32);
            L_[g] += rs;
        }
        __builtin_amdgcn_s_setprio(1);
        #pragma unroll
        for (int kk = 0; kk < 2; ++kk) {
            bf16x8 pa0 = *(const bf16x8*)&Ps[wv][lo][kk * 32 + hi * 8];
            bf16x8 pa1 = *(const bf16x8*)&Ps[wv][16 + lo][kk * 32 + hi * 8];
            #pragma unroll
            for (int f = 0; f < 8; ++f) {
                int row = f * 16 + lo;
                bf16x8 vf = *(const bf16x8*)&Vt[row][(kk * 32 + hi * 8) ^ ((row & 7) << 3)];
                acc[0][f] = MFMA16(pa0, vf, acc[0][f]);
                acc[1][f] = MFMA16(pa1, vf, acc[1][f]);
            }
        }
        __builtin_amdgcn_s_setprio(0);
    }
#undef ISSUE
    const size_t pb = ((size_t)b * CH + slot) * QB;
    #pragma unroll
    for (int g = 0; g < 2; ++g)
        #pragma unroll
        for (int f = 0; f < 8; ++f)
            #pragma unroll
            for (int i = 0; i < 4; ++i) {
                int row = wv * 32 + g * 16 + hi * 4 + i;
                Opart[(pb + row) * 128 + f * 16 + lo] = (bf16)acc[g][f][i];
            }
    if (hi == 0) {
        #pragma unroll
        for (int g = 0; g < 2; ++g) {
            Mpart[pb + wv * 32 + g * 16 + lo] = M_[g];
            Lpart[pb + wv * 32 + g * 16 + lo] = L_[g];
        }
    }
}

// ---------------------------------------------------------------------------
// Kernel 3: combine chunk partials (exp2 domain, bf16 partials).
// grid (NQB*2, B), block 256; each block handles a 128-row half of a q-block.
// ---------------------------------------------------------------------------
__global__ __launch_bounds__(256) void reduce_kernel(
    const bf16* __restrict__ Opart, const float* __restrict__ Mpart,
    const float* __restrict__ Lpart, float* __restrict__ out, int DIV, int CH)
{
    __shared__ float wexp[7][128];
    __shared__ float invL[128];
    const int qb = blockIdx.x >> 1, half = blockIdx.x & 1;
    const int b = blockIdx.y, t = threadIdx.x;
    const int r0 = half * 128;
    int pbase = 0, nact = 1;
    for (int j = 0; j <= qb; ++j) {
        int n = (4 * j + 4 + DIV - 1) / DIV;
        if (j == qb) { nact = n; break; }
        pbase += n;
    }
    const size_t pb = ((size_t)b * CH + pbase) * QB;
    if (t < 128) {
        float Mstar = -INFINITY;
        for (int c = 0; c < nact; ++c)
            Mstar = fmaxf(Mstar, Mpart[pb + c * QB + r0 + t]);
        float Ls = 0.f;
        for (int c = 0; c < nact; ++c) {
            float wc = __builtin_amdgcn_exp2f(Mpart[pb + c * QB + r0 + t] - Mstar);
            wexp[c][t] = wc;
            Ls += wc * Lpart[pb + c * QB + r0 + t];
        }
        invL[t] = 1.f / Ls;
    }
    __syncthreads();
    #pragma unroll
    for (int rep = 0; rep < 16; ++rep) {
        int idx = rep * 256 + t;
        int row = idx >> 5, c4 = (idx & 31) * 4;
        float ox = 0.f, oy = 0.f, oz = 0.f, ow = 0.f;
        for (int c = 0; c < nact; ++c) {
            float wc = wexp[c][row];
            bf16x4 v = *(const bf16x4*)(Opart + (pb + (size_t)c * QB + r0 + row) * 128 + c4);
            ox += wc * (float)v[0]; oy += wc * (float)v[1];
            oz += wc * (float)v[2]; ow += wc * (float)v[3];
        }
        float il = invL[row];
        float4 o = make_float4(ox * il, oy * il, oz * il, ow * il);
        *(float4*)(out + ((size_t)b * Ss + qb * QB + r0 + row) * 128 + c4) = o;
    }
}

extern "C" void kernel_launch(void* const* d_in, const int* in_sizes, int n_in,
                              void* d_out, int out_size, void* d_ws, size_t ws_size,
                              hipStream_t stream) {
    (void)in_sizes; (void)n_in; (void)out_size;
    const float* embds = (const float*)d_in[0];
    const float* Wq = (const float*)d_in[1];
    const float* bq = (const float*)d_in[2];
    const float* Wk = (const float*)d_in[3];
    const float* bk = (const float*)d_in[4];
    const float* Wv = (const float*)d_in[5];
    const float* bv = (const float*)d_in[6];

    char* ws = (char*)d_ws;
    size_t off = 0;
    bf16* Qb    = (bf16*)(ws + off); off += (size_t)Mrows * Hh * 2;
    bf16* Kb    = (bf16*)(ws + off); off += (size_t)Mrows * Hh * 2;
    bf16* Vtg   = (bf16*)(ws + off); off += (size_t)Mrows * Hh * 2;
    bf16* Wfrag = (bf16*)(ws + off); off += (size_t)3 * Hh * Ee * 2;

    auto chunks_for = [](int div) {
        int s = 0;
        for (int qb = 0; qb < NQB; ++qb) s += (4 * qb + 4 + div - 1) / div;
        return s;
    };
    auto need = [&](int ch) {
        return off + (size_t)Bb * ch * QB * 128 * 2 + (size_t)Bb * ch * QB * 8;
    };
    int DIV = 10;
    int CH = chunks_for(DIV);                     // 61
    if (need(CH) > ws_size) { DIV = 20; CH = chunks_for(DIV); }
    bf16* Opart = (bf16*)(ws + off);
    size_t osz = (size_t)Bb * CH * QB * 128 * 2;
    float* Mp = (float*)(ws + off + osz);
    float* Lp = Mp + (size_t)Bb * CH * QB;

    wfrag_kernel<<<dim3(24, 4), 256, 0, stream>>>(Wq, Wk, Wv, Wfrag);
    proj_kernel<<<dim3(Mrows / 64), 512, 0, stream>>>(embds, Wfrag, bq, bk, bv, Qb, Kb, Vtg);
    attn_kernel<<<dim3(CH, Bb), 512, 0, stream>>>(Qb, Kb, Vtg, Opart, Mp, Lp, DIV, CH);
    reduce_kernel<<<dim3(NQB * 2, Bb), 256, 0, stream>>>(Opart, Mp, Lp, (float*)d_out, DIV, CH);
}